// Round 5
// baseline (787.765 us; speedup 1.0000x reference)
//
#include <hip/hip_runtime.h>

#define T_LEN 1024
#define HID   32
#define LDIM  16
#define BATCH 512
#define NT    384   // 3 layers x 2 waves x 64 lanes

typedef _Float16 h2 __attribute__((ext_vector_type(2)));
typedef unsigned int u32;

#if defined(__has_builtin)
#if __has_builtin(__builtin_amdgcn_fdot2)
#define HAVE_FDOT2 1
#endif
#if __has_builtin(__builtin_amdgcn_rcpf)
#define FAST_RCP(x) __builtin_amdgcn_rcpf(x)
#endif
#endif
#ifndef FAST_RCP
#define FAST_RCP(x) (1.0f / (x))
#endif

__device__ __forceinline__ float dot2acc(u32 w, u32 h, float acc) {
#ifdef HAVE_FDOT2
    return __builtin_amdgcn_fdot2(__builtin_bit_cast(h2, w),
                                  __builtin_bit_cast(h2, h), acc, false);
#else
    h2 a = __builtin_bit_cast(h2, w);
    h2 b = __builtin_bit_cast(h2, h);
    return acc + (float)a[0] * (float)b[0] + (float)a[1] * (float)b[1];
#endif
}

__device__ __forceinline__ u32 packh2(float a, float b) {
    h2 v;
    v[0] = (_Float16)a;
    v[1] = (_Float16)b;
    return __builtin_bit_cast(u32, v);
}

// BitMode ds_swizzle: dst lane reads src lane ((lane&0x1F)|0)^xor within 32-lane groups
template <int OFF>
__device__ __forceinline__ float swz(float v) {
    return __builtin_bit_cast(float,
        __builtin_amdgcn_ds_swizzle(__builtin_bit_cast(int, v), OFF));
}

__global__ __launch_bounds__(NT)
__attribute__((amdgpu_waves_per_eu(3, 3)))
void lstm_encoder_kernel(const float* __restrict__ x,
                         const float* __restrict__ Wih0, const float* __restrict__ Whh0,
                         const float* __restrict__ bih0, const float* __restrict__ bhh0,
                         const float* __restrict__ Wih1, const float* __restrict__ Whh1,
                         const float* __restrict__ bih1, const float* __restrict__ bhh1,
                         const float* __restrict__ Wih2, const float* __restrict__ Whh2,
                         const float* __restrict__ bih2, const float* __restrict__ bhh2,
                         const float* __restrict__ Wm,  const float* __restrict__ bm,
                         const float* __restrict__ Wlv, const float* __restrict__ blv,
                         float* __restrict__ out)
{
    const int b    = blockIdx.x;
    const int tid  = threadIdx.x;
    const int lane = tid & 63;
    const int wave = tid >> 6;            // 0..5
    const int l    = wave >> 1;           // layer 0..2 (wave-uniform)
    const int wv   = wave & 1;            // which 16-element group
    const int q    = (lane >> 3) & 3;     // role: 0=i 1=g 2=f 3=o (bits 3,4)
    const int e    = (lane & 7) | ((lane >> 2) & 8);  // element 0..15 (bits 0-2, 5)
    const int j    = wv * 16 + e;         // h element 0..31
    // torch gate-row: i rows 0-31, f 32-63, g 64-95, o 96-127
    const int r = ((q & 1) ? 64 : 0) + ((q & 2) ? 32 : 0) + j;

    __shared__ float xs[T_LEN * 2];                     // 8 KB input stage
    __shared__ __align__(16) _Float16 hb0[3][HID];      // h, buffer parity 0
    __shared__ __align__(16) _Float16 hb1[3][HID];      // h, buffer parity 1
    __shared__ float cbuf[HID];

    // ---- stage x (coalesced, vectorized) ----
    const float4* xb4 = (const float4*)(x + (size_t)b * (T_LEN * 2));
    for (int i = tid; i < (T_LEN * 2) / 4; i += NT) ((float4*)xs)[i] = xb4[i];

    // ---- zero h buffers (48 dwords each) ----
    if (tid < 48)       ((u32*)hb0)[tid]      = 0u;
    else if (tid < 96)  ((u32*)hb1)[tid - 48] = 0u;

    // ---- per-thread weights -> packed f16, order [wih(16) | whh(16)] ----
    const float* Wih = (l == 0) ? Wih0 : (l == 1) ? Wih1 : Wih2;
    const float* Whh = (l == 0) ? Whh0 : (l == 1) ? Whh1 : Whh2;
    const float* bih = (l == 0) ? bih0 : (l == 1) ? bih1 : bih2;
    const float* bhh = (l == 0) ? bhh0 : (l == 1) ? bhh1 : bhh2;

    u32 wpack[32];
    float wx0 = 0.f, wx1 = 0.f;
#pragma unroll
    for (int k = 0; k < 16; ++k)
        wpack[16 + k] = packh2(Whh[r * HID + 2 * k], Whh[r * HID + 2 * k + 1]);
    if (l == 0) {
        wx0 = Wih[r * 2 + 0];
        wx1 = Wih[r * 2 + 1];
#pragma unroll
        for (int k = 0; k < 16; ++k) wpack[k] = 0u;
    } else {
#pragma unroll
        for (int k = 0; k < 16; ++k)
            wpack[k] = packh2(Wih[r * HID + 2 * k], Wih[r * HID + 2 * k + 1]);
    }
    const float bias = bih[r] + bhh[r];
#pragma unroll
    for (int k = 0; k < 32; ++k) asm volatile("" : "+v"(wpack[k]));

    // unified activation: y = mm * sigmoid(kk*x) + aa  (tanh(x) = 2*sigmoid(2x)-1)
    const bool  is_g = (q == 1);
    const float kneg = is_g ? -2.0f : -1.0f;
    const float mm   = is_g ?  2.0f :  1.0f;
    const float aa   = is_g ? -1.0f :  0.0f;

    float c = 0.0f;  // cell value: exact on q0 lanes; bounded garbage elsewhere

    __syncthreads();

#define STEP(RD, WR, S)                                                          \
    do {                                                                         \
        const int t_ = (S) - l;                                                  \
        if ((unsigned)t_ < (unsigned)T_LEN) {                                    \
            float a0 = bias, a1 = 0.f, a2 = 0.f, a3 = 0.f;                       \
            if (l == 0) {                                                        \
                const float2 xv = *(const float2*)&xs[2 * t_];                   \
                a0 = fmaf(wx0, xv.x, a0);                                        \
                a1 = fmaf(wx1, xv.y, a1);                                        \
                const uint4* hv = (const uint4*)&RD[0][0];                       \
                _Pragma("unroll")                                                \
                for (int k = 0; k < 4; ++k) {                                    \
                    const uint4 h = hv[k];                                       \
                    a0 = dot2acc(wpack[16 + 4 * k + 0], h.x, a0);                \
                    a1 = dot2acc(wpack[16 + 4 * k + 1], h.y, a1);                \
                    a2 = dot2acc(wpack[16 + 4 * k + 2], h.z, a2);                \
                    a3 = dot2acc(wpack[16 + 4 * k + 3], h.w, a3);                \
                }                                                                \
            } else {                                                             \
                const uint4* hv = (const uint4*)&RD[l - 1][0];                   \
                _Pragma("unroll")                                                \
                for (int k = 0; k < 8; ++k) {                                    \
                    const uint4 h = hv[k];                                       \
                    a0 = dot2acc(wpack[4 * k + 0], h.x, a0);                     \
                    a1 = dot2acc(wpack[4 * k + 1], h.y, a1);                     \
                    a2 = dot2acc(wpack[4 * k + 2], h.z, a2);                     \
                    a3 = dot2acc(wpack[4 * k + 3], h.w, a3);                     \
                }                                                                \
            }                                                                    \
            const float pre = (a0 + a1) + (a2 + a3);                             \
            const float ex  = __expf(kneg * pre);                                \
            const float y   = fmaf(mm, FAST_RCP(1.0f + ex), aa);                 \
            /* three INDEPENDENT exchanges; meaningful on q0 (y=i): */           \
            const float zg  = swz<0x201F>(y);  /* xor-8:  q0<-q1 (g) */          \
            const float zf  = swz<0x401F>(y);  /* xor-16: q0<-q2 (f) */          \
            const float zo  = swz<0x601F>(y);  /* xor-24: q0<-q3 (o) */          \
            c = fmaf(zf, c, y * zg);           /* on q0: f*c + i*g */            \
            const float e2 = __expf(-2.0f * c);                                  \
            const float th = fmaf(2.0f, FAST_RCP(1.0f + e2), -1.0f);             \
            if (q == 0) WR[l][j] = (_Float16)(zo * th); /* h = o*tanh(c) */      \
        }                                                                        \
        __syncthreads();                                                         \
    } while (0)

    for (int s = 0; s < T_LEN + 2; s += 2) {
        STEP(hb0, hb1, s);
        STEP(hb1, hb0, s + 1);
    }
#undef STEP

    if (l == 2 && q == 0) cbuf[j] = c;
    __syncthreads();

    // ---- final projection: mean / log_var from c3 ----
    if (tid < 2 * LDIM) {
        const bool   is_mean = (tid < LDIM);
        const int    jo = is_mean ? tid : tid - LDIM;
        const float* W  = is_mean ? Wm  : Wlv;
        const float* Bb = is_mean ? bm  : blv;
        float acc = Bb[jo];
#pragma unroll
        for (int k = 0; k < HID; ++k) acc = fmaf(W[jo * HID + k], cbuf[k], acc);
        const size_t off = (is_mean ? 0 : (size_t)BATCH * LDIM) + (size_t)b * LDIM + jo;
        out[off] = acc;
    }
}

extern "C" void kernel_launch(void* const* d_in, const int* in_sizes, int n_in,
                              void* d_out, int out_size, void* d_ws, size_t ws_size,
                              hipStream_t stream) {
    const float* x    = (const float*)d_in[0];
    const float* Wih0 = (const float*)d_in[1];
    const float* Whh0 = (const float*)d_in[2];
    const float* bih0 = (const float*)d_in[3];
    const float* bhh0 = (const float*)d_in[4];
    const float* Wih1 = (const float*)d_in[5];
    const float* Whh1 = (const float*)d_in[6];
    const float* bih1 = (const float*)d_in[7];
    const float* bhh1 = (const float*)d_in[8];
    const float* Wih2 = (const float*)d_in[9];
    const float* Whh2 = (const float*)d_in[10];
    const float* bih2 = (const float*)d_in[11];
    const float* bhh2 = (const float*)d_in[12];
    const float* Wm   = (const float*)d_in[13];
    const float* bm   = (const float*)d_in[14];
    const float* Wlv  = (const float*)d_in[15];
    const float* blv  = (const float*)d_in[16];
    float* out = (float*)d_out;

    lstm_encoder_kernel<<<dim3(BATCH), dim3(NT), 0, stream>>>(
        x, Wih0, Whh0, bih0, bhh0, Wih1, Whh1, bih1, bhh1,
        Wih2, Whh2, bih2, bhh2, Wm, bm, Wlv, blv, out);
}

// Round 6
// 610.286 us; speedup vs baseline: 1.2908x; 1.2908x over previous
//
#include <hip/hip_runtime.h>

#define T_LEN 1024
#define HID   32
#define LDIM  16
#define BATCH 512
#define NT    384   // 3 layers x 2 waves x 64 lanes; block handles 2 batch elems
#define NB    2     // batch elems per block

typedef _Float16 h2 __attribute__((ext_vector_type(2)));
typedef unsigned int u32;

#if defined(__has_builtin)
#if __has_builtin(__builtin_amdgcn_fdot2)
#define HAVE_FDOT2 1
#endif
#if __has_builtin(__builtin_amdgcn_rcpf)
#define FAST_RCP(x) __builtin_amdgcn_rcpf(x)
#endif
#endif
#ifndef FAST_RCP
#define FAST_RCP(x) (1.0f / (x))
#endif

__device__ __forceinline__ float dot2acc(u32 w, u32 h, float acc) {
#ifdef HAVE_FDOT2
    return __builtin_amdgcn_fdot2(__builtin_bit_cast(h2, w),
                                  __builtin_bit_cast(h2, h), acc, false);
#else
    h2 a = __builtin_bit_cast(h2, w);
    h2 b = __builtin_bit_cast(h2, h);
    return acc + (float)a[0] * (float)b[0] + (float)a[1] * (float)b[1];
#endif
}

__device__ __forceinline__ u32 packh2(float a, float b) {
    h2 v;
    v[0] = (_Float16)a;
    v[1] = (_Float16)b;
    return __builtin_bit_cast(u32, v);
}

// BitMode ds_swizzle: dst lane reads src lane (lane&0x1F)^xor within 32-lane groups
template <int OFF>
__device__ __forceinline__ float swz(float v) {
    return __builtin_bit_cast(float,
        __builtin_amdgcn_ds_swizzle(__builtin_bit_cast(int, v), OFF));
}

__global__ __launch_bounds__(NT, 2)
void lstm_encoder_kernel(const float* __restrict__ x,
                         const float* __restrict__ Wih0, const float* __restrict__ Whh0,
                         const float* __restrict__ bih0, const float* __restrict__ bhh0,
                         const float* __restrict__ Wih1, const float* __restrict__ Whh1,
                         const float* __restrict__ bih1, const float* __restrict__ bhh1,
                         const float* __restrict__ Wih2, const float* __restrict__ Whh2,
                         const float* __restrict__ bih2, const float* __restrict__ bhh2,
                         const float* __restrict__ Wm,  const float* __restrict__ bm,
                         const float* __restrict__ Wlv, const float* __restrict__ blv,
                         float* __restrict__ out)
{
    const int b0   = blockIdx.x * NB;     // first batch elem of this block
    const int tid  = threadIdx.x;
    const int lane = tid & 63;
    const int wave = tid >> 6;            // 0..5
    const int l    = wave >> 1;           // layer 0..2 (wave-uniform)
    const int wv   = wave & 1;            // which 16-element group
    const int q    = (lane >> 3) & 3;     // role: 0=i 1=g 2=f 3=o (bits 3,4)
    const int e    = (lane & 7) | ((lane >> 2) & 8);  // element 0..15 (bits 0-2, 5)
    const int j    = wv * 16 + e;         // h element 0..31
    // torch gate-row: i rows 0-31, f 32-63, g 64-95, o 96-127
    const int r = ((q & 1) ? 64 : 0) + ((q & 2) ? 32 : 0) + j;

    __shared__ float xs[NB][T_LEN * 2];                    // 16 KB input stage
    __shared__ __align__(16) _Float16 hb[2][NB][3][HID];   // [parity][elem][layer][j]
    __shared__ float cbuf[NB][HID];

    // ---- stage x (coalesced, vectorized; NB elems contiguous) ----
    const float4* xb4 = (const float4*)(x + (size_t)b0 * (T_LEN * 2));
    for (int i = tid; i < (NB * T_LEN * 2) / 4; i += NT) ((float4*)xs)[i] = xb4[i];

    // ---- zero h buffers (2*NB*3*32 halfs = 192 dwords) ----
    if (tid < 192) ((u32*)hb)[tid] = 0u;

    // ---- per-thread weights -> packed f16, order [wih(16) | whh(16)] ----
    const float* Wih = (l == 0) ? Wih0 : (l == 1) ? Wih1 : Wih2;
    const float* Whh = (l == 0) ? Whh0 : (l == 1) ? Whh1 : Whh2;
    const float* bih = (l == 0) ? bih0 : (l == 1) ? bih1 : bih2;
    const float* bhh = (l == 0) ? bhh0 : (l == 1) ? bhh1 : bhh2;

    u32 wpack[32];
    float wx0 = 0.f, wx1 = 0.f;
#pragma unroll
    for (int k = 0; k < 16; ++k)
        wpack[16 + k] = packh2(Whh[r * HID + 2 * k], Whh[r * HID + 2 * k + 1]);
    if (l == 0) {
        wx0 = Wih[r * 2 + 0];
        wx1 = Wih[r * 2 + 1];
#pragma unroll
        for (int k = 0; k < 16; ++k) wpack[k] = 0u;
    } else {
#pragma unroll
        for (int k = 0; k < 16; ++k)
            wpack[k] = packh2(Wih[r * HID + 2 * k], Wih[r * HID + 2 * k + 1]);
    }
    const float bias = bih[r] + bhh[r];
#pragma unroll
    for (int k = 0; k < 32; ++k) asm volatile("" : "+v"(wpack[k]));

    // unified activation: y = mm * sigmoid(kk*x) + aa  (tanh(x) = 2*sigmoid(2x)-1)
    const bool  is_g = (q == 1);
    const float kneg = is_g ? -2.0f : -1.0f;
    const float mm   = is_g ?  2.0f :  1.0f;
    const float aa   = is_g ? -1.0f :  0.0f;

    float c0 = 0.0f, c1 = 0.0f;  // cell values (exact on q0 lanes)

    __syncthreads();

#define STEP(P, S)                                                               \
    do {                                                                         \
        const int t_ = (S) - l;                                                  \
        if ((unsigned)t_ < (unsigned)T_LEN) {                                    \
            float a00 = bias, a01 = 0.f, a02 = 0.f, a03 = 0.f;                   \
            float a10 = bias, a11 = 0.f, a12 = 0.f, a13 = 0.f;                   \
            if (l == 0) {                                                        \
                const float2 xv0 = *(const float2*)&xs[0][2 * t_];               \
                const float2 xv1 = *(const float2*)&xs[1][2 * t_];               \
                a00 = fmaf(wx0, xv0.x, a00); a01 = fmaf(wx1, xv0.y, a01);        \
                a10 = fmaf(wx0, xv1.x, a10); a11 = fmaf(wx1, xv1.y, a11);        \
                const uint4* hv0 = (const uint4*)&hb[P][0][0][0];                \
                const uint4* hv1 = (const uint4*)&hb[P][1][0][0];                \
                _Pragma("unroll")                                                \
                for (int k = 0; k < 4; ++k) {                                    \
                    const uint4 h0 = hv0[k], h1 = hv1[k];                        \
                    a00 = dot2acc(wpack[16 + 4*k + 0], h0.x, a00);               \
                    a01 = dot2acc(wpack[16 + 4*k + 1], h0.y, a01);               \
                    a02 = dot2acc(wpack[16 + 4*k + 2], h0.z, a02);               \
                    a03 = dot2acc(wpack[16 + 4*k + 3], h0.w, a03);               \
                    a10 = dot2acc(wpack[16 + 4*k + 0], h1.x, a10);               \
                    a11 = dot2acc(wpack[16 + 4*k + 1], h1.y, a11);               \
                    a12 = dot2acc(wpack[16 + 4*k + 2], h1.z, a12);               \
                    a13 = dot2acc(wpack[16 + 4*k + 3], h1.w, a13);               \
                }                                                                \
            } else {                                                             \
                /* contiguous [h_{l-1} | h_l] span matches [wih|whh] order */    \
                const uint4* hv0 = (const uint4*)&hb[P][0][l - 1][0];            \
                const uint4* hv1 = (const uint4*)&hb[P][1][l - 1][0];            \
                _Pragma("unroll")                                                \
                for (int k = 0; k < 8; ++k) {                                    \
                    const uint4 h0 = hv0[k], h1 = hv1[k];                        \
                    a00 = dot2acc(wpack[4*k + 0], h0.x, a00);                    \
                    a01 = dot2acc(wpack[4*k + 1], h0.y, a01);                    \
                    a02 = dot2acc(wpack[4*k + 2], h0.z, a02);                    \
                    a03 = dot2acc(wpack[4*k + 3], h0.w, a03);                    \
                    a10 = dot2acc(wpack[4*k + 0], h1.x, a10);                    \
                    a11 = dot2acc(wpack[4*k + 1], h1.y, a11);                    \
                    a12 = dot2acc(wpack[4*k + 2], h1.z, a12);                    \
                    a13 = dot2acc(wpack[4*k + 3], h1.w, a13);                    \
                }                                                                \
            }                                                                    \
            const float pre0 = (a00 + a01) + (a02 + a03);                        \
            const float pre1 = (a10 + a11) + (a12 + a13);                        \
            const float ex0 = __expf(kneg * pre0);                               \
            const float ex1 = __expf(kneg * pre1);                               \
            const float y0  = fmaf(mm, FAST_RCP(1.0f + ex0), aa);                \
            const float y1  = fmaf(mm, FAST_RCP(1.0f + ex1), aa);                \
            /* three independent exchanges per elem; meaningful on q0 (y=i) */   \
            const float zg0 = swz<0x201F>(y0), zg1 = swz<0x201F>(y1);            \
            const float zf0 = swz<0x401F>(y0), zf1 = swz<0x401F>(y1);            \
            const float zo0 = swz<0x601F>(y0), zo1 = swz<0x601F>(y1);            \
            c0 = fmaf(zf0, c0, y0 * zg0);     /* on q0: f*c + i*g */             \
            c1 = fmaf(zf1, c1, y1 * zg1);                                        \
            const float e20 = __expf(-2.0f * c0);                                \
            const float e21 = __expf(-2.0f * c1);                                \
            const float th0 = fmaf(2.0f, FAST_RCP(1.0f + e20), -1.0f);           \
            const float th1 = fmaf(2.0f, FAST_RCP(1.0f + e21), -1.0f);           \
            if (q == 0) {                                                        \
                hb[(P) ^ 1][0][l][j] = (_Float16)(zo0 * th0);                    \
                hb[(P) ^ 1][1][l][j] = (_Float16)(zo1 * th1);                    \
            }                                                                    \
        }                                                                        \
        __syncthreads();                                                         \
    } while (0)

    for (int s = 0; s < T_LEN + 2; s += 2) {
        STEP(0, s);
        STEP(1, s + 1);
    }
#undef STEP

    if (l == 2 && q == 0) {
        cbuf[0][j] = c0;
        cbuf[1][j] = c1;
    }
    __syncthreads();

    // ---- final projection: mean / log_var from c3 for both elems ----
    if (tid < NB * 2 * LDIM) {
        const int  eo = tid >> 5;            // elem 0/1
        const int  idx = tid & 31;
        const bool is_mean = (idx < LDIM);
        const int  jo = idx & (LDIM - 1);
        const float* W  = is_mean ? Wm  : Wlv;
        const float* Bb = is_mean ? bm  : blv;
        float acc = Bb[jo];
#pragma unroll
        for (int k = 0; k < HID; ++k) acc = fmaf(W[jo * HID + k], cbuf[eo][k], acc);
        const size_t off = (is_mean ? 0 : (size_t)BATCH * LDIM)
                         + (size_t)(b0 + eo) * LDIM + jo;
        out[off] = acc;
    }
}

extern "C" void kernel_launch(void* const* d_in, const int* in_sizes, int n_in,
                              void* d_out, int out_size, void* d_ws, size_t ws_size,
                              hipStream_t stream) {
    const float* x    = (const float*)d_in[0];
    const float* Wih0 = (const float*)d_in[1];
    const float* Whh0 = (const float*)d_in[2];
    const float* bih0 = (const float*)d_in[3];
    const float* bhh0 = (const float*)d_in[4];
    const float* Wih1 = (const float*)d_in[5];
    const float* Whh1 = (const float*)d_in[6];
    const float* bih1 = (const float*)d_in[7];
    const float* bhh1 = (const float*)d_in[8];
    const float* Wih2 = (const float*)d_in[9];
    const float* Whh2 = (const float*)d_in[10];
    const float* bih2 = (const float*)d_in[11];
    const float* bhh2 = (const float*)d_in[12];
    const float* Wm   = (const float*)d_in[13];
    const float* bm   = (const float*)d_in[14];
    const float* Wlv  = (const float*)d_in[15];
    const float* blv  = (const float*)d_in[16];
    float* out = (float*)d_out;

    lstm_encoder_kernel<<<dim3(BATCH / NB), dim3(NT), 0, stream>>>(
        x, Wih0, Whh0, bih0, bhh0, Wih1, Whh1, bih1, bhh1,
        Wih2, Whh2, bih2, bhh2, Wm, bm, Wlv, blv, out);
}

// Round 7
// 590.398 us; speedup vs baseline: 1.3343x; 1.0337x over previous
//
#include <hip/hip_runtime.h>

#define T_LEN 1024
#define HID   32
#define LDIM  16
#define BATCH 512
#define NT    768   // 3 layers x 4 waves x 64 lanes; K split 2-ways across lanes

typedef _Float16 h2 __attribute__((ext_vector_type(2)));
typedef unsigned int u32;

#if defined(__has_builtin)
#if __has_builtin(__builtin_amdgcn_fdot2)
#define HAVE_FDOT2 1
#endif
#if __has_builtin(__builtin_amdgcn_rcpf)
#define FAST_RCP(x) __builtin_amdgcn_rcpf(x)
#endif
#endif
#ifndef FAST_RCP
#define FAST_RCP(x) (1.0f / (x))
#endif

__device__ __forceinline__ float dot2acc(u32 w, u32 h, float acc) {
#ifdef HAVE_FDOT2
    return __builtin_amdgcn_fdot2(__builtin_bit_cast(h2, w),
                                  __builtin_bit_cast(h2, h), acc, false);
#else
    h2 a = __builtin_bit_cast(h2, w);
    h2 b = __builtin_bit_cast(h2, h);
    return acc + (float)a[0] * (float)b[0] + (float)a[1] * (float)b[1];
#endif
}

__device__ __forceinline__ u32 packh2(float a, float b) {
    h2 v;
    v[0] = (_Float16)a;
    v[1] = (_Float16)b;
    return __builtin_bit_cast(u32, v);
}

// BitMode ds_swizzle: dst lane reads src lane (lane&0x1F)^xor within 32-lane groups
template <int OFF>
__device__ __forceinline__ float swz(float v) {
    return __builtin_bit_cast(float,
        __builtin_amdgcn_ds_swizzle(__builtin_bit_cast(int, v), OFF));
}

__global__ __launch_bounds__(NT, 2)
void lstm_encoder_kernel(const float* __restrict__ x,
                         const float* __restrict__ Wih0, const float* __restrict__ Whh0,
                         const float* __restrict__ bih0, const float* __restrict__ bhh0,
                         const float* __restrict__ Wih1, const float* __restrict__ Whh1,
                         const float* __restrict__ bih1, const float* __restrict__ bhh1,
                         const float* __restrict__ Wih2, const float* __restrict__ Whh2,
                         const float* __restrict__ bih2, const float* __restrict__ bhh2,
                         const float* __restrict__ Wm,  const float* __restrict__ bm,
                         const float* __restrict__ Wlv, const float* __restrict__ blv,
                         float* __restrict__ out)
{
    const int b    = blockIdx.x;
    const int tid  = threadIdx.x;
    const int lane = tid & 63;
    const int wave = tid >> 6;            // 0..11
    const int l    = wave >> 2;           // layer 0..2 (wave-uniform)
    const int wl   = wave & 3;            // wave-within-layer: element-high bits
    const int e    = lane & 7;            // element low bits
    const int q    = (lane >> 3) & 3;     // role: 0=i 1=g 2=f 3=o
    const int kh   = lane >> 5;           // K-half 0/1
    const int j    = wl * 8 + e;          // h element 0..31
    // torch gate-row: i rows 0-31, f 32-63, g 64-95, o 96-127
    const int r = ((q & 1) ? 64 : 0) + ((q & 2) ? 32 : 0) + j;

    __shared__ float xs[T_LEN * 2];                  // 8 KB input stage
    __shared__ __align__(16) _Float16 hb0[3][HID];   // h, parity 0
    __shared__ __align__(16) _Float16 hb1[3][HID];   // h, parity 1
    __shared__ float cbuf[HID];

    // ---- stage x (coalesced, vectorized) ----
    const float4* xb4 = (const float4*)(x + (size_t)b * (T_LEN * 2));
    for (int i = tid; i < (T_LEN * 2) / 4; i += NT) ((float4*)xs)[i] = xb4[i];

    // ---- zero h buffers (48 dwords each) ----
    if (tid < 48)       ((u32*)hb0)[tid]      = 0u;
    else if (tid < 96)  ((u32*)hb1)[tid - 48] = 0u;

    // ---- per-thread weights: this lane's K-half, packed f16 [wih(8)|whh(8)] ----
    const float* Wih = (l == 0) ? Wih0 : (l == 1) ? Wih1 : Wih2;
    const float* Whh = (l == 0) ? Whh0 : (l == 1) ? Whh1 : Whh2;
    const float* bih = (l == 0) ? bih0 : (l == 1) ? bih1 : bih2;
    const float* bhh = (l == 0) ? bhh0 : (l == 1) ? bhh1 : bhh2;

    u32 wpack[16];
    float wx0 = 0.f, wx1 = 0.f;
#pragma unroll
    for (int k = 0; k < 8; ++k)
        wpack[8 + k] = packh2(Whh[r * HID + kh * 16 + 2 * k],
                              Whh[r * HID + kh * 16 + 2 * k + 1]);
    if (l == 0) {
        wx0 = Wih[r * 2 + 0];
        wx1 = Wih[r * 2 + 1];
#pragma unroll
        for (int k = 0; k < 8; ++k) wpack[k] = 0u;
    } else {
#pragma unroll
        for (int k = 0; k < 8; ++k)
            wpack[k] = packh2(Wih[r * HID + kh * 16 + 2 * k],
                              Wih[r * HID + kh * 16 + 2 * k + 1]);
    }
    const float bias = bih[r] + bhh[r];
#pragma unroll
    for (int k = 0; k < 16; ++k) asm volatile("" : "+v"(wpack[k]));

    // unified activation: y = mm * sigmoid(kk*x) + aa  (tanh(x) = 2*sigmoid(2x)-1)
    const bool  is_g = (q == 1);
    const float kneg = is_g ? -2.0f : -1.0f;
    const float mm   = is_g ?  2.0f :  1.0f;
    const float aa   = is_g ? -1.0f :  0.0f;

    float c = 0.0f;  // cell value: exact on q0 lanes; bounded garbage elsewhere

    __syncthreads();

#define STEP(RD, WR, S)                                                          \
    do {                                                                         \
        const int t_ = (S) - l;                                                  \
        if ((unsigned)t_ < (unsigned)T_LEN) {                                    \
            float a0 = 0.f, a1 = 0.f, a2 = 0.f, a3 = 0.f;                        \
            const uint4* hvS =                                                   \
                (const uint4*)((const char*)&RD[l][0] + kh * 32);                \
            _Pragma("unroll")                                                    \
            for (int k = 0; k < 2; ++k) {                                        \
                const uint4 h = hvS[k];                                          \
                a0 = dot2acc(wpack[8 + 4 * k + 0], h.x, a0);                     \
                a1 = dot2acc(wpack[8 + 4 * k + 1], h.y, a1);                     \
                a2 = dot2acc(wpack[8 + 4 * k + 2], h.z, a2);                     \
                a3 = dot2acc(wpack[8 + 4 * k + 3], h.w, a3);                     \
            }                                                                    \
            if (l > 0) {                                                         \
                const uint4* hvP =                                               \
                    (const uint4*)((const char*)&RD[l - 1][0] + kh * 32);        \
                _Pragma("unroll")                                                \
                for (int k = 0; k < 2; ++k) {                                    \
                    const uint4 h = hvP[k];                                      \
                    a0 = dot2acc(wpack[4 * k + 0], h.x, a0);                     \
                    a1 = dot2acc(wpack[4 * k + 1], h.y, a1);                     \
                    a2 = dot2acc(wpack[4 * k + 2], h.z, a2);                     \
                    a3 = dot2acc(wpack[4 * k + 3], h.w, a3);                     \
                }                                                                \
            }                                                                    \
            const float rsum = (a0 + a1) + (a2 + a3);                            \
            float pre = bias + rsum + __shfl_xor(rsum, 32, 64);                  \
            if (l == 0) {                                                        \
                const float2 xv = *(const float2*)&xs[2 * t_];                   \
                pre = fmaf(wx0, xv.x, pre);                                      \
                pre = fmaf(wx1, xv.y, pre);                                      \
            }                                                                    \
            const float ex = __expf(kneg * pre);                                 \
            const float y  = fmaf(mm, FAST_RCP(1.0f + ex), aa);                  \
            /* three independent within-32 exchanges; meaningful on q0 (y=i) */  \
            const float zg = swz<0x201F>(y);  /* xor-8:  q0<-q1 (g) */           \
            const float zf = swz<0x401F>(y);  /* xor-16: q0<-q2 (f) */           \
            const float zo = swz<0x601F>(y);  /* xor-24: q0<-q3 (o) */           \
            c = fmaf(zf, c, y * zg);          /* on q0: f*c + i*g */             \
            const float e2 = __expf(-2.0f * c);                                  \
            const float th = fmaf(2.0f, FAST_RCP(1.0f + e2), -1.0f);             \
            if (lane < 8) WR[l][j] = (_Float16)(zo * th); /* q0,kh0: h=o*tanh */ \
        }                                                                        \
        __syncthreads();                                                         \
    } while (0)

    for (int s = 0; s < T_LEN + 2; s += 2) {
        STEP(hb0, hb1, s);
        STEP(hb1, hb0, s + 1);
    }
#undef STEP

    if (l == 2 && lane < 8) cbuf[j] = c;
    __syncthreads();

    // ---- final projection: mean / log_var from c3 ----
    if (tid < 2 * LDIM) {
        const bool   is_mean = (tid < LDIM);
        const int    jo = is_mean ? tid : tid - LDIM;
        const float* W  = is_mean ? Wm  : Wlv;
        const float* Bb = is_mean ? bm  : blv;
        float acc = Bb[jo];
#pragma unroll
        for (int k = 0; k < HID; ++k) acc = fmaf(W[jo * HID + k], cbuf[k], acc);
        const size_t off = (is_mean ? 0 : (size_t)BATCH * LDIM) + (size_t)b * LDIM + jo;
        out[off] = acc;
    }
}

extern "C" void kernel_launch(void* const* d_in, const int* in_sizes, int n_in,
                              void* d_out, int out_size, void* d_ws, size_t ws_size,
                              hipStream_t stream) {
    const float* x    = (const float*)d_in[0];
    const float* Wih0 = (const float*)d_in[1];
    const float* Whh0 = (const float*)d_in[2];
    const float* bih0 = (const float*)d_in[3];
    const float* bhh0 = (const float*)d_in[4];
    const float* Wih1 = (const float*)d_in[5];
    const float* Whh1 = (const float*)d_in[6];
    const float* bih1 = (const float*)d_in[7];
    const float* bhh1 = (const float*)d_in[8];
    const float* Wih2 = (const float*)d_in[9];
    const float* Whh2 = (const float*)d_in[10];
    const float* bih2 = (const float*)d_in[11];
    const float* bhh2 = (const float*)d_in[12];
    const float* Wm   = (const float*)d_in[13];
    const float* bm   = (const float*)d_in[14];
    const float* Wlv  = (const float*)d_in[15];
    const float* blv  = (const float*)d_in[16];
    float* out = (float*)d_out;

    lstm_encoder_kernel<<<dim3(BATCH), dim3(NT), 0, stream>>>(
        x, Wih0, Whh0, bih0, bhh0, Wih1, Whh1, bih1, bhh1,
        Wih2, Whh2, bih2, bhh2, Wm, bm, Wlv, blv, out);
}